// Round 2
// baseline (913.359 us; speedup 1.0000x reference)
//
#include <hip/hip_runtime.h>
#include <hip/hip_bf16.h>

// SA_fusion: B=4, C=512, H=W=64 (HW=4096), fp32 in/out.
// Pipeline: stats -> pack(norm,split-bf16,transpose) -> q/k/v convs (MFMA) ->
//           per-batch [scores (3-term split MFMA, fp32) -> row softmax -> PV] ->
//           final conv + bias + residual.
// Workspace: ~196 MB with explicit aliasing (S/P reuse the packed-input region).
// R1 fix: TB was per-batch (4 MB) instead of all-batch (16 MB) -> Smat overran
// into q/k buffers while the scores GEMM read them -> NaN. Now TB = B*HW*C*2.

typedef __bf16 bf16_t;
typedef __bf16 bf16x8 __attribute__((ext_vector_type(8)));
typedef float f32x4 __attribute__((ext_vector_type(4)));

#define C_DIM 512
#define HW_DIM 4096
#define NBATCH 4
#define CHW (512L * 4096L)

__device__ inline f32x4 mfma_bf16(bf16x8 a, bf16x8 b, f32x4 c) {
    return __builtin_amdgcn_mfma_f32_16x16x32_bf16(a, b, c, 0, 0, 0);
}

// ---------------- stats: mean + rstd (unbiased var, ddof=1) per (b,c) --------
__global__ __launch_bounds__(256) void stats_kernel(
    const float* __restrict__ xc, const float* __restrict__ xs,
    float* __restrict__ meanc, float* __restrict__ rstdc,
    float* __restrict__ means, float* __restrict__ rstds)
{
    int id = blockIdx.x;                 // 0..4095 ; <2048 -> content, else style
    int bc = id & 2047;
    const float* x = (id < 2048 ? xc : xs) + (size_t)bc * HW_DIM;
    int tid = threadIdx.x;
    float s = 0.f, ss = 0.f;
#pragma unroll
    for (int i = 0; i < 16; i++) {
        float v = x[tid + (i << 8)];
        s += v; ss += v * v;
    }
#pragma unroll
    for (int o = 32; o; o >>= 1) { s += __shfl_down(s, o); ss += __shfl_down(ss, o); }
    __shared__ float red[8];
    if ((tid & 63) == 0) { red[(tid >> 6) * 2] = s; red[(tid >> 6) * 2 + 1] = ss; }
    __syncthreads();
    if (tid == 0) {
        s  = red[0] + red[2] + red[4] + red[6];
        ss = red[1] + red[3] + red[5] + red[7];
        float mean = s * (1.0f / 4096.0f);
        float var  = (ss - 4096.0f * mean * mean) * (1.0f / 4095.0f);
        float rstd = rsqrtf(var + 1e-5f);
        if (id < 2048) { meanc[bc] = mean; rstdc[bc] = rstd; }
        else           { means[bc] = mean; rstds[bc] = rstd; }
    }
}

// ---------------- weight pack: fp32 -> bf16 hi/lo ----------------------------
__global__ __launch_bounds__(256) void pack_w_kernel(
    const float* __restrict__ w, bf16_t* __restrict__ h, bf16_t* __restrict__ l, int n)
{
    int i = blockIdx.x * 256 + threadIdx.x;
    if (i < n) {
        float v = w[i];
        bf16_t hh = (bf16_t)v;
        h[i] = hh;
        l[i] = (bf16_t)(v - (float)hh);
    }
}

// ---------------- input pack: (B,C,HW) fp32 -> (B,HW,C) bf16 hi[/lo], opt norm
template<bool NORM, bool WLO>
__global__ __launch_bounds__(256) void pack_T_kernel(
    const float* __restrict__ x, const float* __restrict__ mean, const float* __restrict__ rstd,
    bf16_t* __restrict__ oh, bf16_t* __restrict__ ol)
{
    __shared__ float tile[32][33];
    int b = blockIdx.z, c0 = blockIdx.y * 32, p0 = blockIdx.x * 32;
    int tp = threadIdx.x & 31, tc8 = threadIdx.x >> 5;
    const float* xb = x + ((size_t)b * C_DIM + c0) * HW_DIM + p0;
#pragma unroll
    for (int it = 0; it < 4; it++) {
        int c = tc8 + it * 8;
        float v = xb[(size_t)c * HW_DIM + tp];
        if constexpr (NORM) {
            float m = mean[b * C_DIM + c0 + c];
            float r = rstd[b * C_DIM + c0 + c];
            v = (v - m) * r;
        }
        tile[c][tp] = v;
    }
    __syncthreads();
    int wc = threadIdx.x & 31, wp8 = threadIdx.x >> 5;
    bf16_t* ohb = oh + ((size_t)b * HW_DIM + p0) * C_DIM + c0;
#pragma unroll
    for (int it = 0; it < 4; it++) {
        int p = wp8 + it * 8;
        float v = tile[wc][p];
        bf16_t h = (bf16_t)v;
        ohb[(size_t)p * C_DIM + wc] = h;
        if constexpr (WLO) {
            bf16_t lo = (bf16_t)(v - (float)h);
            ol[((size_t)b * HW_DIM + p0 + p) * C_DIM + c0 + wc] = lo;
        }
    }
}

// ---------------- row softmax: S fp32 (4096x4096) -> P bf16, normalized ------
__global__ __launch_bounds__(256) void softmax_rows(
    const float* __restrict__ S, bf16_t* __restrict__ P)
{
    int row = blockIdx.x;
    int tid = threadIdx.x;
    int wave = tid >> 6, lane = tid & 63;
    const float* sr = S + (size_t)row * HW_DIM;
    float v[16];
    float mx = -3.4e38f;
#pragma unroll
    for (int i = 0; i < 16; i++) { v[i] = sr[tid + (i << 8)]; mx = fmaxf(mx, v[i]); }
#pragma unroll
    for (int o = 32; o; o >>= 1) mx = fmaxf(mx, __shfl_down(mx, o));
    __shared__ float red[4];
    if (lane == 0) red[wave] = mx;
    __syncthreads();
    mx = fmaxf(fmaxf(red[0], red[1]), fmaxf(red[2], red[3]));
    float sum = 0.f;
#pragma unroll
    for (int i = 0; i < 16; i++) { v[i] = __expf(v[i] - mx); sum += v[i]; }
#pragma unroll
    for (int o = 32; o; o >>= 1) sum += __shfl_down(sum, o);
    __syncthreads();
    if (lane == 0) red[wave] = sum;
    __syncthreads();
    sum = red[0] + red[1] + red[2] + red[3];
    float inv = 1.0f / sum;
    bf16_t* pr = P + (size_t)row * HW_DIM;
#pragma unroll
    for (int i = 0; i < 16; i++) pr[tid + (i << 8)] = (bf16_t)(v[i] * inv);
}

// ---------------- NT GEMM template: C[m][n] = sum_k A[m][k]*B[n][k] ----------
// lda == ldb == K (rows K-contiguous). 16x16x32 bf16 MFMA, block=256 (2x2 waves).
// SPLIT: 3-term hi/lo product for ~fp32-grade accuracy.
// EPI: 0 = fp32 normal [m][n] (+opt bias[m], +opt residual same layout)
//      1 = bf16 normal [m][n] (+bias)
//      2 = transposed split bf16 [n][m] (+bias), ldc = transposed pitch
//      3 = transposed bf16 [n][m]
template<int WM, int WN, int EPI, bool SPLIT>
__global__ __launch_bounds__(256) void gemm_nt(
    const bf16_t* __restrict__ Ah, const bf16_t* __restrict__ Al,
    const bf16_t* __restrict__ Bh, const bf16_t* __restrict__ Bl,
    void* __restrict__ Cout0, void* __restrict__ Cout1,
    const float* __restrict__ bias, const float* __restrict__ resid,
    int K, int ldc,
    long sAz, long sBz, long sCz, long sRz)
{
    constexpr int BM = 2 * WM * 16;
    constexpr int BN = 2 * WN * 16;
    constexpr int BK = 32, BKP = 40;   // +8 bf16 pad: 2-way max bank aliasing (free)
    constexpr int NT = (SPLIT ? 2 : 1);
    __shared__ __align__(16) bf16_t smem[NT * (BM + BN) * BKP];
    bf16_t* sAh = smem;
    bf16_t* sAl = smem + BM * BKP;            // used iff SPLIT
    bf16_t* sBh = smem + NT * BM * BKP;
    bf16_t* sBl = sBh + BN * BKP;             // used iff SPLIT

    const int tid  = threadIdx.x;
    const int wave = tid >> 6, lane = tid & 63;
    const int wm = (wave >> 1) * (WM * 16);
    const int wn = (wave & 1) * (WN * 16);
    const int fr = lane & 15;
    const int fk = (lane >> 4) * 8;
    const int srow = tid >> 2;
    const int scol = (tid & 3) * 8;

    const long mBlock = (long)blockIdx.y * BM;
    const long nBlock = (long)blockIdx.x * BN;
    const int z = blockIdx.z;
    const bf16_t* Az  = Ah + (size_t)z * sAz;
    const bf16_t* Bz  = Bh + (size_t)z * sBz;
    const bf16_t* Azl = SPLIT ? (Al + (size_t)z * sAz) : nullptr;
    const bf16_t* Bzl = SPLIT ? (Bl + (size_t)z * sBz) : nullptr;

    f32x4 acc[WM][WN];
#pragma unroll
    for (int i = 0; i < WM; i++)
#pragma unroll
        for (int j = 0; j < WN; j++)
            acc[i][j] = (f32x4){0.f, 0.f, 0.f, 0.f};

    for (int k0 = 0; k0 < K; k0 += BK) {
        __syncthreads();
#pragma unroll
        for (int r0 = 0; r0 < BM; r0 += 64) {
            int r = r0 + srow;
            *reinterpret_cast<uint4*>(sAh + r * BKP + scol) =
                *reinterpret_cast<const uint4*>(Az + (size_t)(mBlock + r) * K + k0 + scol);
            if (SPLIT)
                *reinterpret_cast<uint4*>(sAl + r * BKP + scol) =
                    *reinterpret_cast<const uint4*>(Azl + (size_t)(mBlock + r) * K + k0 + scol);
        }
#pragma unroll
        for (int r0 = 0; r0 < BN; r0 += 64) {
            int r = r0 + srow;
            *reinterpret_cast<uint4*>(sBh + r * BKP + scol) =
                *reinterpret_cast<const uint4*>(Bz + (size_t)(nBlock + r) * K + k0 + scol);
            if (SPLIT)
                *reinterpret_cast<uint4*>(sBl + r * BKP + scol) =
                    *reinterpret_cast<const uint4*>(Bzl + (size_t)(nBlock + r) * K + k0 + scol);
        }
        __syncthreads();

        bf16x8 ah[WM], bh[WN], alo[WM], blo[WN];
#pragma unroll
        for (int i = 0; i < WM; i++) {
            ah[i] = *reinterpret_cast<const bf16x8*>(sAh + (wm + i * 16 + fr) * BKP + fk);
            if (SPLIT)
                alo[i] = *reinterpret_cast<const bf16x8*>(sAl + (wm + i * 16 + fr) * BKP + fk);
        }
#pragma unroll
        for (int j = 0; j < WN; j++) {
            bh[j] = *reinterpret_cast<const bf16x8*>(sBh + (wn + j * 16 + fr) * BKP + fk);
            if (SPLIT)
                blo[j] = *reinterpret_cast<const bf16x8*>(sBl + (wn + j * 16 + fr) * BKP + fk);
        }
#pragma unroll
        for (int i = 0; i < WM; i++)
#pragma unroll
            for (int j = 0; j < WN; j++) {
                acc[i][j] = mfma_bf16(ah[i], bh[j], acc[i][j]);
                if (SPLIT) {
                    acc[i][j] = mfma_bf16(ah[i], blo[j], acc[i][j]);
                    acc[i][j] = mfma_bf16(alo[i], bh[j], acc[i][j]);
                }
            }
    }

    // epilogue. D layout: col(n)=lane&15, row(m)=(lane>>4)*4+reg
    const int col  = lane & 15;
    const int rowq = (lane >> 4) * 4;
#pragma unroll
    for (int i = 0; i < WM; i++) {
        const long mb = mBlock + wm + i * 16 + rowq;
        float bv[4];
#pragma unroll
        for (int r = 0; r < 4; r++) bv[r] = bias ? bias[mb + r] : 0.0f;
#pragma unroll
        for (int j = 0; j < WN; j++) {
            const long n = nBlock + wn + j * 16 + col;
            float v[4];
#pragma unroll
            for (int r = 0; r < 4; r++) v[r] = acc[i][j][r] + bv[r];
            if constexpr (EPI == 0) {
                float* O = (float*)Cout0 + (size_t)z * sCz;
                const float* R = resid ? (resid + (size_t)z * sRz) : nullptr;
#pragma unroll
                for (int r = 0; r < 4; r++) {
                    size_t off = (size_t)(mb + r) * ldc + n;
                    O[off] = v[r] + (R ? R[off] : 0.0f);
                }
            } else if constexpr (EPI == 1) {
                bf16_t* O = (bf16_t*)Cout0 + (size_t)z * sCz;
#pragma unroll
                for (int r = 0; r < 4; r++) O[(size_t)(mb + r) * ldc + n] = (bf16_t)v[r];
            } else if constexpr (EPI == 2) {
                alignas(8) bf16_t h[4], l[4];
#pragma unroll
                for (int r = 0; r < 4; r++) {
                    h[r] = (bf16_t)v[r];
                    l[r] = (bf16_t)(v[r] - (float)h[r]);
                }
                size_t off = (size_t)z * sCz + (size_t)n * ldc + mb;
                *reinterpret_cast<uint2*>((bf16_t*)Cout0 + off) = *reinterpret_cast<uint2*>(h);
                *reinterpret_cast<uint2*>((bf16_t*)Cout1 + off) = *reinterpret_cast<uint2*>(l);
            } else {
                alignas(8) bf16_t h[4];
#pragma unroll
                for (int r = 0; r < 4; r++) h[r] = (bf16_t)v[r];
                size_t off = (size_t)z * sCz + (size_t)n * ldc + mb;
                *reinterpret_cast<uint2*>((bf16_t*)Cout0 + off) = *reinterpret_cast<uint2*>(h);
            }
        }
    }
}

// ---------------------------------------------------------------------------
extern "C" void kernel_launch(void* const* d_in, const int* in_sizes, int n_in,
                              void* d_out, int out_size, void* d_ws, size_t ws_size,
                              hipStream_t stream)
{
    const float* x_fcc = (const float*)d_in[0];
    const float* x_fss = (const float*)d_in[1];
    const float* w1 = (const float*)d_in[2];
    const float* b1 = (const float*)d_in[3];
    const float* w2 = (const float*)d_in[4];
    const float* b2 = (const float*)d_in[5];
    const float* w3 = (const float*)d_in[6];
    const float* b3 = (const float*)d_in[7];
    const float* wrs = (const float*)d_in[8];
    const float* brs = (const float*)d_in[9];
    float* out = (float*)d_out;

    char* base = (char*)d_ws;
    size_t off = 0;
    auto take = [&](size_t bytes) -> char* {
        char* p = base + off;
        off += (bytes + 255) & ~(size_t)255;
        return p;
    };
    const size_t WB = (size_t)C_DIM * C_DIM * sizeof(bf16_t);        // 512 KB
    const size_t TB = (size_t)NBATCH * CHW * sizeof(bf16_t);         // 16 MB (ALL batches)

    float* meanc = (float*)take(2048 * 4);
    float* rstdc = (float*)take(2048 * 4);
    float* means = (float*)take(2048 * 4);
    float* rstds = (float*)take(2048 * 4);
    bf16_t* w1h = (bf16_t*)take(WB); bf16_t* w1l = (bf16_t*)take(WB);
    bf16_t* w2h = (bf16_t*)take(WB); bf16_t* w2l = (bf16_t*)take(WB);
    bf16_t* w3h = (bf16_t*)take(WB); bf16_t* w3l = (bf16_t*)take(WB);
    bf16_t* wrh = (bf16_t*)take(WB); bf16_t* wrl = (bf16_t*)take(WB);
    // 96 MB region: phase-1 packed inputs; phase-2 aliases S (64MB) + P (32MB)
    char* packb = take(6 * TB);
    bf16_t* xcTh = (bf16_t*)(packb);
    bf16_t* xcTl = (bf16_t*)(packb + TB);
    bf16_t* xsTh = (bf16_t*)(packb + 2 * TB);
    bf16_t* xsTl = (bf16_t*)(packb + 3 * TB);
    bf16_t* xsrT = (bf16_t*)(packb + 4 * TB);
    float*  Smat = (float*)(packb);            // 64 MB, aliases xcTh..xsTl (dead after q/k convs)
    bf16_t* Pmat = (bf16_t*)(packb + 4 * TB);  // 32 MB, aliases xsrT (dead after v conv) + spare
    bf16_t* qTh = (bf16_t*)take(TB);
    bf16_t* qTl = (bf16_t*)take(TB);
    bf16_t* kTh = (bf16_t*)take(TB);
    bf16_t* kTl = (bf16_t*)take(TB);
    bf16_t* vh  = (bf16_t*)take(TB);
    bf16_t* frsT = (bf16_t*)take(TB);
    (void)ws_size; (void)n_in; (void)in_sizes; (void)out_size;

    dim3 blk(256);

    // 1. stats
    stats_kernel<<<dim3(4096), blk, 0, stream>>>(x_fcc, x_fss, meanc, rstdc, means, rstds);
    // 2. weight packs
    pack_w_kernel<<<dim3(1024), blk, 0, stream>>>(w1, w1h, w1l, C_DIM * C_DIM);
    pack_w_kernel<<<dim3(1024), blk, 0, stream>>>(w2, w2h, w2l, C_DIM * C_DIM);
    pack_w_kernel<<<dim3(1024), blk, 0, stream>>>(w3, w3h, w3l, C_DIM * C_DIM);
    pack_w_kernel<<<dim3(1024), blk, 0, stream>>>(wrs, wrh, wrl, C_DIM * C_DIM);
    // 3. input packs (normalized content/style split, raw style)
    pack_T_kernel<true, true><<<dim3(128, 16, 4), blk, 0, stream>>>(x_fcc, meanc, rstdc, xcTh, xcTl);
    pack_T_kernel<true, true><<<dim3(128, 16, 4), blk, 0, stream>>>(x_fss, means, rstds, xsTh, xsTl);
    pack_T_kernel<false, false><<<dim3(128, 16, 4), blk, 0, stream>>>(x_fss, nullptr, nullptr, xsrT, nullptr);
    // 4. q/k convs: 3-term split, transposed split-bf16 out [p][c]
    gemm_nt<4, 4, 2, true><<<dim3(32, 4, 4), blk, 0, stream>>>(
        w1h, w1l, xcTh, xcTl, qTh, qTl, b1, nullptr, C_DIM, C_DIM, 0L, CHW, CHW, 0L);
    gemm_nt<4, 4, 2, true><<<dim3(32, 4, 4), blk, 0, stream>>>(
        w2h, w2l, xsTh, xsTl, kTh, kTl, b2, nullptr, C_DIM, C_DIM, 0L, CHW, CHW, 0L);
    // 5. v conv: plain bf16, normal layout [c][p]
    gemm_nt<4, 4, 1, false><<<dim3(32, 4, 4), blk, 0, stream>>>(
        w3h, nullptr, xsrT, nullptr, vh, nullptr, b3, nullptr, C_DIM, HW_DIM, 0L, CHW, CHW, 0L);
    // 6. per-batch attention (S/P buffers reused; stream-ordered)
    for (int b = 0; b < NBATCH; b++) {
        gemm_nt<4, 4, 0, true><<<dim3(32, 32, 1), blk, 0, stream>>>(
            qTh + (size_t)b * CHW, qTl + (size_t)b * CHW,
            kTh + (size_t)b * CHW, kTl + (size_t)b * CHW,
            Smat, nullptr, nullptr, nullptr, C_DIM, HW_DIM, 0L, 0L, 0L, 0L);
        softmax_rows<<<dim3(4096), blk, 0, stream>>>(Smat, Pmat);
        gemm_nt<2, 4, 3, false><<<dim3(32, 8, 1), blk, 0, stream>>>(
            vh + (size_t)b * CHW, nullptr, Pmat, nullptr,
            frsT + (size_t)b * CHW, nullptr, nullptr, nullptr, HW_DIM, C_DIM, 0L, 0L, 0L, 0L);
    }
    // 7. final conv + bias + residual -> fp32 out
    gemm_nt<4, 4, 0, false><<<dim3(32, 4, 4), blk, 0, stream>>>(
        wrh, nullptr, frsT, nullptr, out, nullptr, brs, x_fcc, C_DIM, HW_DIM, 0L, CHW, CHW, CHW);
}

// Round 3
// 882.407 us; speedup vs baseline: 1.0351x; 1.0351x over previous
//
#include <hip/hip_runtime.h>
#include <hip/hip_bf16.h>

// SA_fusion: B=4, C=512, H=W=64 (HW=4096), fp32 in/out.
// R3: async global->LDS staging (global_load_lds width 16, unpadded [row][32]
// LDS tiles), float4-vectorized softmax/stats, fused pack launches.

typedef __bf16 bf16_t;
typedef __bf16 bf16x8 __attribute__((ext_vector_type(8)));
typedef float f32x4 __attribute__((ext_vector_type(4)));

#define C_DIM 512
#define HW_DIM 4096
#define NBATCH 4
#define CHW (512L * 4096L)

__device__ inline f32x4 mfma_bf16(bf16x8 a, bf16x8 b, f32x4 c) {
    return __builtin_amdgcn_mfma_f32_16x16x32_bf16(a, b, c, 0, 0, 0);
}

// async 16B/lane global->LDS. LDS dest is wave-uniform base; lane i lands at
// base + i*16. Generic->AS casts via integer round-trip (low 32 bits of a
// generic LDS pointer are the AS3 offset on gfx9).
__device__ inline void g2l16(const bf16_t* g, bf16_t* l) {
    auto gp = (const __attribute__((address_space(1))) uint32_t*)(uintptr_t)g;
    auto lp = (__attribute__((address_space(3))) uint32_t*)(uint32_t)(uintptr_t)l;
    __builtin_amdgcn_global_load_lds(gp, lp, 16, 0, 0);
}

// ---------------- stats: mean + rstd (unbiased var, ddof=1) per (b,c) --------
__global__ __launch_bounds__(256) void stats_kernel(
    const float* __restrict__ xc, const float* __restrict__ xs,
    float* __restrict__ meanc, float* __restrict__ rstdc,
    float* __restrict__ means, float* __restrict__ rstds)
{
    int id = blockIdx.x;                 // 0..4095 ; <2048 -> content, else style
    int bc = id & 2047;
    const float4* x = (const float4*)((id < 2048 ? xc : xs) + (size_t)bc * HW_DIM);
    int tid = threadIdx.x;
    float s = 0.f, ss = 0.f;
#pragma unroll
    for (int i = 0; i < 4; i++) {
        float4 v = x[tid + (i << 8)];
        s += v.x + v.y + v.z + v.w;
        ss += v.x * v.x + v.y * v.y + v.z * v.z + v.w * v.w;
    }
#pragma unroll
    for (int o = 32; o; o >>= 1) { s += __shfl_down(s, o); ss += __shfl_down(ss, o); }
    __shared__ float red[8];
    if ((tid & 63) == 0) { red[(tid >> 6) * 2] = s; red[(tid >> 6) * 2 + 1] = ss; }
    __syncthreads();
    if (tid == 0) {
        s  = red[0] + red[2] + red[4] + red[6];
        ss = red[1] + red[3] + red[5] + red[7];
        float mean = s * (1.0f / 4096.0f);
        float var  = (ss - 4096.0f * mean * mean) * (1.0f / 4095.0f);
        float rstd = rsqrtf(var + 1e-5f);
        if (id < 2048) { meanc[bc] = mean; rstdc[bc] = rstd; }
        else           { means[bc] = mean; rstds[bc] = rstd; }
    }
}

// ---------------- weight pack: fp32 -> bf16 hi/lo, 4 weights in one grid -----
__global__ __launch_bounds__(256) void pack_w4_kernel(
    const float* __restrict__ w0, const float* __restrict__ w1,
    const float* __restrict__ w2, const float* __restrict__ w3,
    bf16_t* __restrict__ h0, bf16_t* __restrict__ h1,
    bf16_t* __restrict__ h2, bf16_t* __restrict__ h3,
    bf16_t* __restrict__ l0, bf16_t* __restrict__ l1,
    bf16_t* __restrict__ l2, bf16_t* __restrict__ l3)
{
    int which = blockIdx.y;
    const float* w = which == 0 ? w0 : which == 1 ? w1 : which == 2 ? w2 : w3;
    bf16_t* h = which == 0 ? h0 : which == 1 ? h1 : which == 2 ? h2 : h3;
    bf16_t* l = which == 0 ? l0 : which == 1 ? l1 : which == 2 ? l2 : l3;
    int i = blockIdx.x * 256 + threadIdx.x;   // grid.x*256 == 262144 exactly
    float v = w[i];
    bf16_t hh = (bf16_t)v;
    h[i] = hh;
    l[i] = (bf16_t)(v - (float)hh);
}

// ---------------- input pack: (B,C,HW) fp32 -> (B,HW,C) bf16 hi[/lo] ---------
// z = b + 4*src; src 0: content norm split, 1: style norm split, 2: style raw
__global__ __launch_bounds__(256) void pack_T_kernel(
    const float* __restrict__ xc, const float* __restrict__ xs,
    const float* __restrict__ meanc, const float* __restrict__ rstdc,
    const float* __restrict__ means, const float* __restrict__ rstds,
    bf16_t* __restrict__ ch, bf16_t* __restrict__ cl,
    bf16_t* __restrict__ sh, bf16_t* __restrict__ sl,
    bf16_t* __restrict__ sraw)
{
    __shared__ float tile[32][33];
    int z = blockIdx.z;
    int b = z & 3, src = z >> 2;
    const float* x    = (src == 0) ? xc : xs;
    const float* mean = (src == 0) ? meanc : means;
    const float* rstd = (src == 0) ? rstdc : rstds;
    bf16_t* oh = (src == 0) ? ch : (src == 1) ? sh : sraw;
    bf16_t* ol = (src == 0) ? cl : sl;
    bool norm = (src < 2);

    int c0 = blockIdx.y * 32, p0 = blockIdx.x * 32;
    int tp = threadIdx.x & 31, tc8 = threadIdx.x >> 5;
    const float* xb = x + ((size_t)b * C_DIM + c0) * HW_DIM + p0;
#pragma unroll
    for (int it = 0; it < 4; it++) {
        int c = tc8 + it * 8;
        float v = xb[(size_t)c * HW_DIM + tp];
        if (norm) {
            float m = mean[b * C_DIM + c0 + c];
            float r = rstd[b * C_DIM + c0 + c];
            v = (v - m) * r;
        }
        tile[c][tp] = v;
    }
    __syncthreads();
    int wc = threadIdx.x & 31, wp8 = threadIdx.x >> 5;
    bf16_t* ohb = oh + ((size_t)b * HW_DIM + p0) * C_DIM + c0;
#pragma unroll
    for (int it = 0; it < 4; it++) {
        int p = wp8 + it * 8;
        float v = tile[wc][p];
        bf16_t h = (bf16_t)v;
        ohb[(size_t)p * C_DIM + wc] = h;
        if (norm) {
            bf16_t lo = (bf16_t)(v - (float)h);
            ol[((size_t)b * HW_DIM + p0 + p) * C_DIM + c0 + wc] = lo;
        }
    }
}

// ---------------- row softmax: S fp32 (4096x4096) -> P bf16, normalized ------
__global__ __launch_bounds__(256) void softmax_rows(
    const float* __restrict__ S, bf16_t* __restrict__ P)
{
    int row = blockIdx.x;
    int tid = threadIdx.x;
    int wave = tid >> 6, lane = tid & 63;
    const float4* sr = (const float4*)(S + (size_t)row * HW_DIM);
    float4 v[4];
    float mx = -3.4e38f;
#pragma unroll
    for (int i = 0; i < 4; i++) {
        v[i] = sr[tid + (i << 8)];
        mx = fmaxf(mx, fmaxf(fmaxf(v[i].x, v[i].y), fmaxf(v[i].z, v[i].w)));
    }
#pragma unroll
    for (int o = 32; o; o >>= 1) mx = fmaxf(mx, __shfl_down(mx, o));
    __shared__ float red[4];
    if (lane == 0) red[wave] = mx;
    __syncthreads();
    mx = fmaxf(fmaxf(red[0], red[1]), fmaxf(red[2], red[3]));
    float sum = 0.f;
#pragma unroll
    for (int i = 0; i < 4; i++) {
        v[i].x = __expf(v[i].x - mx); v[i].y = __expf(v[i].y - mx);
        v[i].z = __expf(v[i].z - mx); v[i].w = __expf(v[i].w - mx);
        sum += v[i].x + v[i].y + v[i].z + v[i].w;
    }
#pragma unroll
    for (int o = 32; o; o >>= 1) sum += __shfl_down(sum, o);
    __syncthreads();
    if (lane == 0) red[wave] = sum;
    __syncthreads();
    sum = red[0] + red[1] + red[2] + red[3];
    float inv = 1.0f / sum;
    uint2* pr = (uint2*)(P + (size_t)row * HW_DIM);
#pragma unroll
    for (int i = 0; i < 4; i++) {
        union { uint2 u; bf16_t h[4]; } o;
        o.h[0] = (bf16_t)(v[i].x * inv); o.h[1] = (bf16_t)(v[i].y * inv);
        o.h[2] = (bf16_t)(v[i].z * inv); o.h[3] = (bf16_t)(v[i].w * inv);
        pr[tid + (i << 8)] = o.u;
    }
}

// ---------------- NT GEMM template: C[m][n] = sum_k A[m][k]*B[n][k] ----------
// Rows K-contiguous. 16x16x32 bf16 MFMA, block=256 (2x2 waves).
// Staging: async global_load_lds width 16; LDS tiles unpadded [row][32]
// (64B rows). One wave-call stages a 1KB segment = 16 rows; lane l supplies
// global addr of row seg*16+(l>>2), bytes (l&3)*16 -> lands at base+l*16. ✓
// SPLIT: 3-term hi/lo product for ~fp32-grade accuracy.
// EPI: 0 = fp32 [m][n] (+opt bias[m], +opt residual); 1 = bf16 [m][n] (+bias)
//      2 = transposed split bf16 [n][m] (+bias); 3 = transposed bf16 [n][m]
template<int WM, int WN, int EPI, bool SPLIT>
__global__ __launch_bounds__(256) void gemm_nt(
    const bf16_t* __restrict__ Ah, const bf16_t* __restrict__ Al,
    const bf16_t* __restrict__ Bh, const bf16_t* __restrict__ Bl,
    void* __restrict__ Cout0, void* __restrict__ Cout1,
    const float* __restrict__ bias, const float* __restrict__ resid,
    int K, int ldc,
    long sAz, long sBz, long sCz, long sRz)
{
    constexpr int BM = 2 * WM * 16;
    constexpr int BN = 2 * WN * 16;
    constexpr int BK = 32;
    constexpr int NT = (SPLIT ? 2 : 1);
    __shared__ __align__(16) bf16_t smem[NT * (BM + BN) * BK];
    bf16_t* sAh = smem;
    bf16_t* sAl = smem + BM * BK;             // used iff SPLIT
    bf16_t* sBh = smem + NT * BM * BK;
    bf16_t* sBl = sBh + BN * BK;              // used iff SPLIT

    const int tid  = threadIdx.x;
    const int wave = tid >> 6, lane = tid & 63;
    const int wm = (wave >> 1) * (WM * 16);
    const int wn = (wave & 1) * (WN * 16);
    const int fr = lane & 15;
    const int fk = (lane >> 4) * 8;
    const int srow = lane >> 2;          // row within 16-row segment
    const int scol = (lane & 3) * 8;     // elem offset within row (16B)

    const long mBlock = (long)blockIdx.y * BM;
    const long nBlock = (long)blockIdx.x * BN;
    const int z = blockIdx.z;
    const bf16_t* Az  = Ah + (size_t)z * sAz;
    const bf16_t* Bz  = Bh + (size_t)z * sBz;
    const bf16_t* Azl = SPLIT ? (Al + (size_t)z * sAz) : nullptr;
    const bf16_t* Bzl = SPLIT ? (Bl + (size_t)z * sBz) : nullptr;

    // per-lane staging base pointers (advance by BK each iter)
    const bf16_t* gA  = Az + (size_t)(mBlock + srow) * K + scol;
    const bf16_t* gB  = Bz + (size_t)(nBlock + srow) * K + scol;
    const bf16_t* gAl = SPLIT ? (Azl + (size_t)(mBlock + srow) * K + scol) : nullptr;
    const bf16_t* gBl = SPLIT ? (Bzl + (size_t)(nBlock + srow) * K + scol) : nullptr;

    f32x4 acc[WM][WN];
#pragma unroll
    for (int i = 0; i < WM; i++)
#pragma unroll
        for (int j = 0; j < WN; j++)
            acc[i][j] = (f32x4){0.f, 0.f, 0.f, 0.f};

    for (int k0 = 0; k0 < K; k0 += BK) {
        __syncthreads();                       // prior tile fully consumed
#pragma unroll
        for (int s = 0; s < BM / 16; s += 4) {
            int seg = s + wave;
            g2l16(gA + (size_t)seg * 16 * K + k0, sAh + seg * 512);
            if (SPLIT)
                g2l16(gAl + (size_t)seg * 16 * K + k0, sAl + seg * 512);
        }
#pragma unroll
        for (int s = 0; s < BN / 16; s += 4) {
            int seg = s + wave;
            g2l16(gB + (size_t)seg * 16 * K + k0, sBh + seg * 512);
            if (SPLIT)
                g2l16(gBl + (size_t)seg * 16 * K + k0, sBl + seg * 512);
        }
        __syncthreads();                       // drains vmcnt (async loads done)

        bf16x8 ah[WM], bh[WN], alo[WM], blo[WN];
#pragma unroll
        for (int i = 0; i < WM; i++) {
            ah[i] = *reinterpret_cast<const bf16x8*>(sAh + (wm + i * 16 + fr) * BK + fk);
            if (SPLIT)
                alo[i] = *reinterpret_cast<const bf16x8*>(sAl + (wm + i * 16 + fr) * BK + fk);
        }
#pragma unroll
        for (int j = 0; j < WN; j++) {
            bh[j] = *reinterpret_cast<const bf16x8*>(sBh + (wn + j * 16 + fr) * BK + fk);
            if (SPLIT)
                blo[j] = *reinterpret_cast<const bf16x8*>(sBl + (wn + j * 16 + fr) * BK + fk);
        }
#pragma unroll
        for (int i = 0; i < WM; i++)
#pragma unroll
            for (int j = 0; j < WN; j++) {
                acc[i][j] = mfma_bf16(ah[i], bh[j], acc[i][j]);
                if (SPLIT) {
                    acc[i][j] = mfma_bf16(ah[i], blo[j], acc[i][j]);
                    acc[i][j] = mfma_bf16(alo[i], bh[j], acc[i][j]);
                }
            }
    }

    // epilogue. D layout: col(n)=lane&15, row(m)=(lane>>4)*4+reg
    const int col  = lane & 15;
    const int rowq = (lane >> 4) * 4;
#pragma unroll
    for (int i = 0; i < WM; i++) {
        const long mb = mBlock + wm + i * 16 + rowq;
        float bv[4];
#pragma unroll
        for (int r = 0; r < 4; r++) bv[r] = bias ? bias[mb + r] : 0.0f;
#pragma unroll
        for (int j = 0; j < WN; j++) {
            const long n = nBlock + wn + j * 16 + col;
            float v[4];
#pragma unroll
            for (int r = 0; r < 4; r++) v[r] = acc[i][j][r] + bv[r];
            if constexpr (EPI == 0) {
                float* O = (float*)Cout0 + (size_t)z * sCz;
                const float* R = resid ? (resid + (size_t)z * sRz) : nullptr;
#pragma unroll
                for (int r = 0; r < 4; r++) {
                    size_t off = (size_t)(mb + r) * ldc + n;
                    O[off] = v[r] + (R ? R[off] : 0.0f);
                }
            } else if constexpr (EPI == 1) {
                bf16_t* O = (bf16_t*)Cout0 + (size_t)z * sCz;
#pragma unroll
                for (int r = 0; r < 4; r++) O[(size_t)(mb + r) * ldc + n] = (bf16_t)v[r];
            } else if constexpr (EPI == 2) {
                alignas(8) bf16_t h[4], l[4];
#pragma unroll
                for (int r = 0; r < 4; r++) {
                    h[r] = (bf16_t)v[r];
                    l[r] = (bf16_t)(v[r] - (float)h[r]);
                }
                size_t off = (size_t)z * sCz + (size_t)n * ldc + mb;
                *reinterpret_cast<uint2*>((bf16_t*)Cout0 + off) = *reinterpret_cast<uint2*>(h);
                *reinterpret_cast<uint2*>((bf16_t*)Cout1 + off) = *reinterpret_cast<uint2*>(l);
            } else {
                alignas(8) bf16_t h[4];
#pragma unroll
                for (int r = 0; r < 4; r++) h[r] = (bf16_t)v[r];
                size_t off = (size_t)z * sCz + (size_t)n * ldc + mb;
                *reinterpret_cast<uint2*>((bf16_t*)Cout0 + off) = *reinterpret_cast<uint2*>(h);
            }
        }
    }
}

// ---------------------------------------------------------------------------
extern "C" void kernel_launch(void* const* d_in, const int* in_sizes, int n_in,
                              void* d_out, int out_size, void* d_ws, size_t ws_size,
                              hipStream_t stream)
{
    const float* x_fcc = (const float*)d_in[0];
    const float* x_fss = (const float*)d_in[1];
    const float* w1 = (const float*)d_in[2];
    const float* b1 = (const float*)d_in[3];
    const float* w2 = (const float*)d_in[4];
    const float* b2 = (const float*)d_in[5];
    const float* w3 = (const float*)d_in[6];
    const float* b3 = (const float*)d_in[7];
    const float* wrs = (const float*)d_in[8];
    const float* brs = (const float*)d_in[9];
    float* out = (float*)d_out;

    char* base = (char*)d_ws;
    size_t off = 0;
    auto take = [&](size_t bytes) -> char* {
        char* p = base + off;
        off += (bytes + 255) & ~(size_t)255;
        return p;
    };
    const size_t WB = (size_t)C_DIM * C_DIM * sizeof(bf16_t);        // 512 KB
    const size_t TB = (size_t)NBATCH * CHW * sizeof(bf16_t);         // 16 MB (ALL batches)

    float* meanc = (float*)take(2048 * 4);
    float* rstdc = (float*)take(2048 * 4);
    float* means = (float*)take(2048 * 4);
    float* rstds = (float*)take(2048 * 4);
    bf16_t* w1h = (bf16_t*)take(WB); bf16_t* w1l = (bf16_t*)take(WB);
    bf16_t* w2h = (bf16_t*)take(WB); bf16_t* w2l = (bf16_t*)take(WB);
    bf16_t* w3h = (bf16_t*)take(WB); bf16_t* w3l = (bf16_t*)take(WB);
    bf16_t* wrh = (bf16_t*)take(WB); bf16_t* wrl = (bf16_t*)take(WB);
    // 96 MB region: phase-1 packed inputs; phase-2 aliases S (64MB) + P (32MB)
    char* packb = take(6 * TB);
    bf16_t* xcTh = (bf16_t*)(packb);
    bf16_t* xcTl = (bf16_t*)(packb + TB);
    bf16_t* xsTh = (bf16_t*)(packb + 2 * TB);
    bf16_t* xsTl = (bf16_t*)(packb + 3 * TB);
    bf16_t* xsrT = (bf16_t*)(packb + 4 * TB);
    float*  Smat = (float*)(packb);            // 64 MB, aliases xcTh..xsTl (dead after q/k convs)
    bf16_t* Pmat = (bf16_t*)(packb + 4 * TB);  // 32 MB, aliases xsrT (dead after v conv) + spare
    bf16_t* qTh = (bf16_t*)take(TB);
    bf16_t* qTl = (bf16_t*)take(TB);
    bf16_t* kTh = (bf16_t*)take(TB);
    bf16_t* kTl = (bf16_t*)take(TB);
    bf16_t* vh  = (bf16_t*)take(TB);
    bf16_t* frsT = (bf16_t*)take(TB);
    (void)ws_size; (void)n_in; (void)in_sizes; (void)out_size;

    dim3 blk(256);

    // 1. stats
    stats_kernel<<<dim3(4096), blk, 0, stream>>>(x_fcc, x_fss, meanc, rstdc, means, rstds);
    // 2. weight packs (fused)
    pack_w4_kernel<<<dim3(1024, 4), blk, 0, stream>>>(
        w1, w2, w3, wrs, w1h, w2h, w3h, wrh, w1l, w2l, w3l, wrl);
    // 3. input packs (fused: content norm, style norm, style raw)
    pack_T_kernel<<<dim3(128, 16, 12), blk, 0, stream>>>(
        x_fcc, x_fss, meanc, rstdc, means, rstds, xcTh, xcTl, xsTh, xsTl, xsrT);
    // 4. q/k convs: 3-term split, transposed split-bf16 out [p][c]
    gemm_nt<4, 4, 2, true><<<dim3(32, 4, 4), blk, 0, stream>>>(
        w1h, w1l, xcTh, xcTl, qTh, qTl, b1, nullptr, C_DIM, C_DIM, 0L, CHW, CHW, 0L);
    gemm_nt<4, 4, 2, true><<<dim3(32, 4, 4), blk, 0, stream>>>(
        w2h, w2l, xsTh, xsTl, kTh, kTl, b2, nullptr, C_DIM, C_DIM, 0L, CHW, CHW, 0L);
    // 5. v conv: plain bf16, normal layout [c][p]
    gemm_nt<4, 4, 1, false><<<dim3(32, 4, 4), blk, 0, stream>>>(
        w3h, nullptr, xsrT, nullptr, vh, nullptr, b3, nullptr, C_DIM, HW_DIM, 0L, CHW, CHW, 0L);
    // 6. per-batch attention (S/P buffers reused; stream-ordered)
    for (int b = 0; b < NBATCH; b++) {
        gemm_nt<4, 4, 0, true><<<dim3(32, 32, 1), blk, 0, stream>>>(
            qTh + (size_t)b * CHW, qTl + (size_t)b * CHW,
            kTh + (size_t)b * CHW, kTl + (size_t)b * CHW,
            Smat, nullptr, nullptr, nullptr, C_DIM, HW_DIM, 0L, 0L, 0L, 0L);
        softmax_rows<<<dim3(4096), blk, 0, stream>>>(Smat, Pmat);
        gemm_nt<2, 4, 3, false><<<dim3(32, 8, 1), blk, 0, stream>>>(
            vh + (size_t)b * CHW, nullptr, Pmat, nullptr,
            frsT + (size_t)b * CHW, nullptr, nullptr, nullptr, HW_DIM, C_DIM, 0L, 0L, 0L, 0L);
    }
    // 7. final conv + bias + residual -> fp32 out
    gemm_nt<4, 4, 0, false><<<dim3(32, 4, 4), blk, 0, stream>>>(
        wrh, nullptr, frsT, nullptr, out, nullptr, brs, x_fcc, C_DIM, HW_DIM, 0L, CHW, CHW, CHW);
}